// Round 4
// baseline (255.245 us; speedup 1.0000x reference)
//
#include <hip/hip_runtime.h>
#include <hip/hip_bf16.h>
#include <math.h>

#define BB 32
#define SS 4096
#define HH 256

typedef __bf16 bf16x8 __attribute__((ext_vector_type(8)));
typedef float f32x4 __attribute__((ext_vector_type(4)));

#define GLOBAL_AS __attribute__((address_space(1)))
#define LDS_AS    __attribute__((address_space(3)))

__device__ inline bf16x8 cvt8(const float4& x, const float4& y) {
    union { __hip_bfloat162 p[4]; bf16x8 v; } u;
    u.p[0] = __float22bfloat162_rn(make_float2(x.x, x.y));
    u.p[1] = __float22bfloat162_rn(make_float2(x.z, x.w));
    u.p[2] = __float22bfloat162_rn(make_float2(y.x, y.y));
    u.p[3] = __float22bfloat162_rn(make_float2(y.z, y.w));
    return u.v;
}

// tanh via exp path: ~6 VALU ops. |rel err| ~1e-7.
__device__ inline float fast_tanh(float x) {
    float xc = fminf(fmaxf(x, -10.f), 10.f);
    float e  = __expf(2.f * xc);
    return (e - 1.f) * __builtin_amdgcn_rcpf(e + 1.f);
}

// ---------------------------------------------------------------------------
// Prep (fused): blocks 0..255 swizzle W2 -> bf16 MFMA-B order;
// blocks 256..287: qq[b][h] = hidden[b]@W1[:,h] + W1_b[h] + W2_b[h].
// w2sw[((kc*16+nt)*64+lane)*8+j] = W2[kc*32+(lane>>4)*8+j][nt*16+(lane&15)]
// ---------------------------------------------------------------------------
__global__ void prep_kernel(const float* __restrict__ W2_w,
                            ushort* __restrict__ w2sw,
                            const float* __restrict__ hidden,
                            const float* __restrict__ W1_w,
                            const float* __restrict__ W1_b,
                            const float* __restrict__ W2_b,
                            float* __restrict__ qq) {
    __shared__ float hid[HH];
    const int t = threadIdx.x;
    if (blockIdx.x < 256) {
        const int i = blockIdx.x * 256 + t;
        const int j    = i & 7;
        const int lane = (i >> 3) & 63;
        const int nt   = (i >> 9) & 15;
        const int kc   = i >> 13;
        const int k = kc * 32 + ((lane >> 4) & 3) * 8 + j;
        const int n = nt * 16 + (lane & 15);
        __hip_bfloat16 h = __float2bfloat16(W2_w[k * HH + n]);
        w2sw[i] = *(ushort*)&h;
    } else {
        const int b = blockIdx.x - 256;
        hid[t] = hidden[b * HH + t];
        __syncthreads();
        float acc = 0.f;
#pragma unroll 16
        for (int k = 0; k < HH; ++k)
            acc = fmaf(hid[k], W1_w[k * HH + t], acc);
        qq[b * HH + t] = acc + W1_b[t] + W2_b[t];
    }
}

// ---------------------------------------------------------------------------
// Score kernel: grid (SS/64, BB), block 256 = 4 waves as 2(m) x 2(n).
// Block tile 64 s-rows x 256 n. Wave (mw,nw): rows mw*32 + {0,16}+..,
// cols nw*128. acc = 2 mt x 8 nt x f32x4 = 64 regs -> 4 waves/SIMD.
// Each b-frag ds_read feeds 2 MFMAs (halved LDS traffic vs R3).
// W2 K-chunks double-buffered via global_load_lds width 16.
// Emits scores + per-block (m, sum-exp) partials.
// ---------------------------------------------------------------------------
__global__ __launch_bounds__(256, 4)
void score_kernel(const float* __restrict__ enc,
                  const ushort* __restrict__ w2sw,
                  const float* __restrict__ qq,
                  const float* __restrict__ V_w,
                  const float* __restrict__ V_b,
                  float* __restrict__ scores,
                  float* __restrict__ mlpart) {
    __shared__ ushort w2buf[2][8192];   // 2 x 16 KB
    __shared__ float sc_lds[64];

    const int t    = threadIdx.x;
    const int b    = blockIdx.y;
    const int s0   = blockIdx.x * 64;
    const int wave = t >> 6;
    const int lane = t & 63;
    const int mw   = wave & 1;
    const int nw   = wave >> 1;
    const int l15  = lane & 15;
    const int quad = lane >> 4;

    f32x4 acc[2][8];
#pragma unroll
    for (int mt = 0; mt < 2; ++mt)
#pragma unroll
        for (int nt = 0; nt < 8; ++nt) acc[mt][nt] = (f32x4)0.f;

    // stage W2 chunk 0 -> buf 0 (4 sweeps x 4 KB)
    {
        const char* gsrc = (const char*)w2sw + t * 16;
        char* ldst = (char*)&w2buf[0][0] + wave * 1024;
#pragma unroll
        for (int i = 0; i < 4; ++i)
            __builtin_amdgcn_global_load_lds(
                (const GLOBAL_AS void*)(gsrc + i * 4096),
                (LDS_AS void*)(ldst + i * 4096), 16, 0, 0);
    }

    // A: rows s0 + mw*32 + mt*16 + l15, k = kc*32 + quad*8 + j
    const float* aptr0 =
        enc + ((size_t)(b * SS + s0 + mw * 32 + l15)) * HH + quad * 8;
    const float* aptr1 = aptr0 + (size_t)16 * HH;
    float4 ax0 = *(const float4*)aptr0, ay0 = *(const float4*)(aptr0 + 4);
    float4 ax1 = *(const float4*)aptr1, ay1 = *(const float4*)(aptr1 + 4);

    for (int kc = 0; kc < 8; ++kc) {
        const int cur = kc & 1;
        __syncthreads();   // chunk kc resident; prefetched A in regs
        if (kc < 7) {
            const char* gsrc = (const char*)w2sw + (kc + 1) * 16384 + t * 16;
            char* ldst = (char*)&w2buf[cur ^ 1][0] + wave * 1024;
#pragma unroll
            for (int i = 0; i < 4; ++i)
                __builtin_amdgcn_global_load_lds(
                    (const GLOBAL_AS void*)(gsrc + i * 4096),
                    (LDS_AS void*)(ldst + i * 4096), 16, 0, 0);
        }
        bf16x8 af0 = cvt8(ax0, ay0);
        bf16x8 af1 = cvt8(ax1, ay1);
        if (kc < 7) {
            const int o = (kc + 1) * 32;
            ax0 = *(const float4*)(aptr0 + o);
            ay0 = *(const float4*)(aptr0 + o + 4);
            ax1 = *(const float4*)(aptr1 + o);
            ay1 = *(const float4*)(aptr1 + o + 4);
        }
#pragma unroll
        for (int nt = 0; nt < 8; ++nt) {
            bf16x8 bf =
                *(const bf16x8*)&w2buf[cur][((nw * 8 + nt) * 64 + lane) * 8];
            acc[0][nt] = __builtin_amdgcn_mfma_f32_16x16x32_bf16(af0, bf, acc[0][nt], 0, 0, 0);
            acc[1][nt] = __builtin_amdgcn_mfma_f32_16x16x32_bf16(af1, bf, acc[1][nt], 0, 0, 0);
        }
    }

    // Epilogue: C layout col = l15, local row = quad*4 + r.
    float p[2][4] = {{0.f, 0.f, 0.f, 0.f}, {0.f, 0.f, 0.f, 0.f}};
#pragma unroll
    for (int nt = 0; nt < 8; ++nt) {
        const int n = nw * 128 + nt * 16 + l15;
        const float qn = qq[b * HH + n];
        const float vn = V_w[n];
#pragma unroll
        for (int mt = 0; mt < 2; ++mt)
#pragma unroll
            for (int r = 0; r < 4; ++r)
                p[mt][r] = fmaf(vn, fast_tanh(qn + acc[mt][nt][r]), p[mt][r]);
    }
#pragma unroll
    for (int off = 1; off < 16; off <<= 1)
#pragma unroll
        for (int mt = 0; mt < 2; ++mt)
#pragma unroll
            for (int r = 0; r < 4; ++r)
                p[mt][r] += __shfl_xor(p[mt][r], off);

    if (nw == 0 && l15 == 0) {
#pragma unroll
        for (int mt = 0; mt < 2; ++mt)
            *(float4*)&sc_lds[mw * 32 + mt * 16 + quad * 4] =
                make_float4(p[mt][0], p[mt][1], p[mt][2], p[mt][3]);
    }
    __syncthreads();
    const float vb = V_b[0];
    if (nw == 1 && l15 == 0) {
#pragma unroll
        for (int mt = 0; mt < 2; ++mt) {
            const int row = mw * 32 + mt * 16 + quad * 4;
            float4 h = *(const float4*)&sc_lds[row];
            float4 v = make_float4(h.x + p[mt][0] + vb, h.y + p[mt][1] + vb,
                                   h.z + p[mt][2] + vb, h.w + p[mt][3] + vb);
            *(float4*)&sc_lds[row] = v;
            *(float4*)&scores[b * SS + s0 + row] = v;
        }
    }
    __syncthreads();

    if (t < 64) {
        const float v = sc_lds[t];
        float m = v;
#pragma unroll
        for (int off = 1; off < 64; off <<= 1)
            m = fmaxf(m, __shfl_xor(m, off));
        float e = __expf(v - m);
#pragma unroll
        for (int off = 1; off < 64; off <<= 1)
            e += __shfl_xor(e, off);
        if (t == 0) {
            mlpart[(b * 64 + blockIdx.x) * 2]     = m;
            mlpart[(b * 64 + blockIdx.x) * 2 + 1] = e;
        }
    }
}

// ---------------------------------------------------------------------------
// ctx kernel: grid (64, BB), block 256, 64 s-rows per chunk.
// Merges the 64 (m,l) partials in-register, writes weights (d_out),
// accumulates partial context, atomicAdd into ctx_out (zeroed via memset).
// ---------------------------------------------------------------------------
__global__ __launch_bounds__(256)
void ctx_kernel(const float* __restrict__ scores,
                const float* __restrict__ mlpart,
                const float* __restrict__ enc,
                float* __restrict__ weights_out,
                float* __restrict__ ctx_out) {
    __shared__ float wlds[64];
    __shared__ float accl[4][HH];
    __shared__ float mg_s, linv_s;

    const int t  = threadIdx.x;
    const int b  = blockIdx.y;
    const int c  = blockIdx.x;
    const int s0 = c * 64;

    if (t < 64) {
        const float2 ml = ((const float2*)mlpart)[b * 64 + t];
        float m = ml.x;
#pragma unroll
        for (int off = 1; off < 64; off <<= 1)
            m = fmaxf(m, __shfl_xor(m, off));
        float l = ml.y * __expf(ml.x - m);
#pragma unroll
        for (int off = 1; off < 64; off <<= 1)
            l += __shfl_xor(l, off);
        if (t == 0) { mg_s = m; linv_s = 1.f / l; }
    }
    __syncthreads();
    const float mg = mg_s, linv = linv_s;

    if (t < 64) {
        const float w = __expf(scores[b * SS + s0 + t] - mg) * linv;
        weights_out[b * SS + s0 + t] = w;
        wlds[t] = w;
    }
    __syncthreads();

    // thread (tr = t>>6, h0 = (t&63)*4): rows j = jj*4 + tr
    const int tr = t >> 6;
    const int h0 = (t & 63) * 4;
    float4 a = make_float4(0.f, 0.f, 0.f, 0.f);
    const float* ep = enc + ((size_t)(b * SS + s0)) * HH;
#pragma unroll
    for (int jj = 0; jj < 16; ++jj) {
        const int j = jj * 4 + tr;
        const float4 e = *(const float4*)(ep + (size_t)j * HH + h0);
        const float w = wlds[j];
        a.x = fmaf(w, e.x, a.x);
        a.y = fmaf(w, e.y, a.y);
        a.z = fmaf(w, e.z, a.z);
        a.w = fmaf(w, e.w, a.w);
    }
    *(float4*)&accl[tr][h0] = a;
    __syncthreads();

    const float s = accl[0][t] + accl[1][t] + accl[2][t] + accl[3][t];
    atomicAdd(&ctx_out[b * HH + t], s);
}

// ---------------------------------------------------------------------------
extern "C" void kernel_launch(void* const* d_in, const int* in_sizes, int n_in,
                              void* d_out, int out_size, void* d_ws, size_t ws_size,
                              hipStream_t stream) {
    const float* hidden = (const float*)d_in[0];
    const float* enc    = (const float*)d_in[1];
    const float* W1_w   = (const float*)d_in[2];
    const float* W1_b   = (const float*)d_in[3];
    const float* W2_w   = (const float*)d_in[4];
    const float* W2_b   = (const float*)d_in[5];
    const float* V_w    = (const float*)d_in[6];
    const float* V_b    = (const float*)d_in[7];

    float* out_weights = (float*)d_out;                 // B*S
    float* out_ctx     = (float*)d_out + BB * SS;       // B*H

    float* ws     = (float*)d_ws;
    float* ws_qq  = ws;                                  // 8192
    float* ws_sc  = ws_qq + BB * HH;                     // 131072
    float* ws_ml  = ws_sc + BB * SS;                     // 4096
    ushort* ws_w2 = (ushort*)(ws_ml + BB * 64 * 2);      // 65536 bf16

    hipMemsetAsync(out_ctx, 0, BB * HH * sizeof(float), stream);
    prep_kernel<<<dim3(256 + BB), dim3(256), 0, stream>>>(
        W2_w, ws_w2, hidden, W1_w, W1_b, W2_b, ws_qq);
    score_kernel<<<dim3(SS / 64, BB), dim3(256), 0, stream>>>(
        enc, ws_w2, ws_qq, V_w, V_b, ws_sc, ws_ml);
    ctx_kernel<<<dim3(64, BB), dim3(256), 0, stream>>>(
        ws_sc, ws_ml, enc, out_weights, out_ctx);
}

// Round 5
// 247.182 us; speedup vs baseline: 1.0326x; 1.0326x over previous
//
#include <hip/hip_runtime.h>
#include <hip/hip_bf16.h>
#include <math.h>

#define BB 32
#define SS 4096
#define HH 256

typedef __bf16 bf16x8 __attribute__((ext_vector_type(8)));
typedef float f32x4 __attribute__((ext_vector_type(4)));

#define GLOBAL_AS __attribute__((address_space(1)))
#define LDS_AS    __attribute__((address_space(3)))

__device__ inline bf16x8 cvt8(const float4& x, const float4& y) {
    union { __hip_bfloat162 p[4]; bf16x8 v; } u;
    u.p[0] = __float22bfloat162_rn(make_float2(x.x, x.y));
    u.p[1] = __float22bfloat162_rn(make_float2(x.z, x.w));
    u.p[2] = __float22bfloat162_rn(make_float2(y.x, y.y));
    u.p[3] = __float22bfloat162_rn(make_float2(y.z, y.w));
    return u.v;
}

// tanh via exp path: ~6 VALU ops. |rel err| ~1e-7.
__device__ inline float fast_tanh(float x) {
    float xc = fminf(fmaxf(x, -10.f), 10.f);
    float e  = __expf(2.f * xc);
    return (e - 1.f) * __builtin_amdgcn_rcpf(e + 1.f);
}

// ---------------------------------------------------------------------------
// Prep (fused): blocks 0..255 swizzle W2 -> bf16 MFMA-B order;
// blocks 256..287: qq[b][h] = hidden[b]@W1[:,h] + W1_b[h] + W2_b[h];
// block 288: M = sum_h |V_w[h]|  (upper bound on V.tanh; V_b cancels in
// the shifted softmax, so it is never added anywhere).
// w2sw[((kc*16+nt)*64+lane)*8+j] = W2[kc*32+(lane>>4)*8+j][nt*16+(lane&15)]
// ---------------------------------------------------------------------------
__global__ void prep_kernel(const float* __restrict__ W2_w,
                            ushort* __restrict__ w2sw,
                            const float* __restrict__ hidden,
                            const float* __restrict__ W1_w,
                            const float* __restrict__ W1_b,
                            const float* __restrict__ W2_b,
                            const float* __restrict__ V_w,
                            float* __restrict__ qq,
                            float* __restrict__ Mout) {
    __shared__ float red[HH];
    const int t = threadIdx.x;
    if (blockIdx.x < 256) {
        const int i = blockIdx.x * 256 + t;
        const int j    = i & 7;
        const int lane = (i >> 3) & 63;
        const int nt   = (i >> 9) & 15;
        const int kc   = i >> 13;
        const int k = kc * 32 + ((lane >> 4) & 3) * 8 + j;
        const int n = nt * 16 + (lane & 15);
        __hip_bfloat16 h = __float2bfloat16(W2_w[k * HH + n]);
        w2sw[i] = *(ushort*)&h;
    } else if (blockIdx.x < 256 + BB) {
        const int b = blockIdx.x - 256;
        red[t] = hidden[b * HH + t];
        __syncthreads();
        float acc = 0.f;
#pragma unroll 16
        for (int k = 0; k < HH; ++k)
            acc = fmaf(red[k], W1_w[k * HH + t], acc);
        qq[b * HH + t] = acc + W1_b[t] + W2_b[t];
    } else {
        red[t] = fabsf(V_w[t]);
        __syncthreads();
        for (int off = 128; off > 0; off >>= 1) {
            if (t < off) red[t] += red[t + off];
            __syncthreads();
        }
        if (t == 0) Mout[0] = red[0];
    }
}

// ---------------------------------------------------------------------------
// Fused score + partial-context kernel: grid (SS/64, BB), block 256
// = 4 waves as 2(m) x 2(n). Block tile 64 s-rows x 256 n.
// 1) GEMM k = enc_tile @ W2 (MFMA, W2 K-chunks double-buffered in LDS).
// 2) Epilogue: s' = sum_n V[n]*tanh(qq[n] + k[n]); wtilde = exp(s' - M).
// 3) Local context partial: re-read own enc rows (L1/L2-hot),
//    part[b,c,:] = sum_{s in tile} wtilde_s * enc_s. No second enc pass.
// ---------------------------------------------------------------------------
__global__ __launch_bounds__(256, 4)
void score_ctx_kernel(const float* __restrict__ enc,
                      const ushort* __restrict__ w2sw,
                      const float* __restrict__ qq,
                      const float* __restrict__ V_w,
                      const float* __restrict__ Mptr,
                      float* __restrict__ wtilde,
                      float* __restrict__ part) {
    __shared__ ushort w2buf[2][8192];   // 2 x 16 KB
    __shared__ float sc_lds[64];
    __shared__ float accl[4][HH];

    const int t    = threadIdx.x;
    const int b    = blockIdx.y;
    const int c    = blockIdx.x;
    const int s0   = c * 64;
    const int wave = t >> 6;
    const int lane = t & 63;
    const int mw   = wave & 1;
    const int nw   = wave >> 1;
    const int l15  = lane & 15;
    const int quad = lane >> 4;

    f32x4 acc[2][8];
#pragma unroll
    for (int mt = 0; mt < 2; ++mt)
#pragma unroll
        for (int nt = 0; nt < 8; ++nt) acc[mt][nt] = (f32x4)0.f;

    // stage W2 chunk 0 -> buf 0 (4 sweeps x 4 KB)
    {
        const char* gsrc = (const char*)w2sw + t * 16;
        char* ldst = (char*)&w2buf[0][0] + wave * 1024;
#pragma unroll
        for (int i = 0; i < 4; ++i)
            __builtin_amdgcn_global_load_lds(
                (const GLOBAL_AS void*)(gsrc + i * 4096),
                (LDS_AS void*)(ldst + i * 4096), 16, 0, 0);
    }

    // A: rows s0 + mw*32 + mt*16 + l15, k = kc*32 + quad*8 + j
    const float* aptr0 =
        enc + ((size_t)(b * SS + s0 + mw * 32 + l15)) * HH + quad * 8;
    const float* aptr1 = aptr0 + (size_t)16 * HH;
    float4 ax0 = *(const float4*)aptr0, ay0 = *(const float4*)(aptr0 + 4);
    float4 ax1 = *(const float4*)aptr1, ay1 = *(const float4*)(aptr1 + 4);

    for (int kc = 0; kc < 8; ++kc) {
        const int cur = kc & 1;
        __syncthreads();   // chunk kc resident; prefetched A in regs
        if (kc < 7) {
            const char* gsrc = (const char*)w2sw + (kc + 1) * 16384 + t * 16;
            char* ldst = (char*)&w2buf[cur ^ 1][0] + wave * 1024;
#pragma unroll
            for (int i = 0; i < 4; ++i)
                __builtin_amdgcn_global_load_lds(
                    (const GLOBAL_AS void*)(gsrc + i * 4096),
                    (LDS_AS void*)(ldst + i * 4096), 16, 0, 0);
        }
        bf16x8 af0 = cvt8(ax0, ay0);
        bf16x8 af1 = cvt8(ax1, ay1);
        if (kc < 7) {
            const int o = (kc + 1) * 32;
            ax0 = *(const float4*)(aptr0 + o);
            ay0 = *(const float4*)(aptr0 + o + 4);
            ax1 = *(const float4*)(aptr1 + o);
            ay1 = *(const float4*)(aptr1 + o + 4);
        }
#pragma unroll
        for (int nt = 0; nt < 8; ++nt) {
            bf16x8 bf =
                *(const bf16x8*)&w2buf[cur][((nw * 8 + nt) * 64 + lane) * 8];
            acc[0][nt] = __builtin_amdgcn_mfma_f32_16x16x32_bf16(af0, bf, acc[0][nt], 0, 0, 0);
            acc[1][nt] = __builtin_amdgcn_mfma_f32_16x16x32_bf16(af1, bf, acc[1][nt], 0, 0, 0);
        }
    }

    // Epilogue: C layout col = l15, local row = quad*4 + r.
    float p[2][4] = {{0.f, 0.f, 0.f, 0.f}, {0.f, 0.f, 0.f, 0.f}};
#pragma unroll
    for (int nt = 0; nt < 8; ++nt) {
        const int n = nw * 128 + nt * 16 + l15;
        const float qn = qq[b * HH + n];
        const float vn = V_w[n];
#pragma unroll
        for (int mt = 0; mt < 2; ++mt)
#pragma unroll
            for (int r = 0; r < 4; ++r)
                p[mt][r] = fmaf(vn, fast_tanh(qn + acc[mt][nt][r]), p[mt][r]);
    }
#pragma unroll
    for (int off = 1; off < 16; off <<= 1)
#pragma unroll
        for (int mt = 0; mt < 2; ++mt)
#pragma unroll
            for (int r = 0; r < 4; ++r)
                p[mt][r] += __shfl_xor(p[mt][r], off);

    if (nw == 0 && l15 == 0) {
#pragma unroll
        for (int mt = 0; mt < 2; ++mt)
            *(float4*)&sc_lds[mw * 32 + mt * 16 + quad * 4] =
                make_float4(p[mt][0], p[mt][1], p[mt][2], p[mt][3]);
    }
    __syncthreads();
    const float Mv = Mptr[0];
    if (nw == 1 && l15 == 0) {
#pragma unroll
        for (int mt = 0; mt < 2; ++mt) {
            const int row = mw * 32 + mt * 16 + quad * 4;
            float4 h = *(const float4*)&sc_lds[row];
            float4 v = make_float4(__expf(h.x + p[mt][0] - Mv),
                                   __expf(h.y + p[mt][1] - Mv),
                                   __expf(h.z + p[mt][2] - Mv),
                                   __expf(h.w + p[mt][3] - Mv));
            *(float4*)&sc_lds[row] = v;
            *(float4*)&wtilde[b * SS + s0 + row] = v;
        }
    }
    __syncthreads();

    // Local context partial over this block's 64 rows (enc slice is L1/L2-hot).
    const int tr = t >> 6;
    const int h0 = (t & 63) * 4;
    float4 a = make_float4(0.f, 0.f, 0.f, 0.f);
    const float* ep = enc + ((size_t)(b * SS + s0)) * HH;
#pragma unroll
    for (int jj = 0; jj < 16; ++jj) {
        const int j = jj * 4 + tr;
        const float4 e = *(const float4*)(ep + (size_t)j * HH + h0);
        const float w = sc_lds[j];
        a.x = fmaf(w, e.x, a.x);
        a.y = fmaf(w, e.y, a.y);
        a.z = fmaf(w, e.z, a.z);
        a.w = fmaf(w, e.w, a.w);
    }
    *(float4*)&accl[tr][h0] = a;
    __syncthreads();

    part[((size_t)(b * 64 + c)) * HH + t] =
        accl[0][t] + accl[1][t] + accl[2][t] + accl[3][t];
}

// ---------------------------------------------------------------------------
// Finish: grid (BB), block 256. l = sum_s wtilde; weights = wtilde/l;
// ctx = (sum_c part)/l.
// ---------------------------------------------------------------------------
__global__ __launch_bounds__(256)
void finish_kernel(const float* __restrict__ wtilde,
                   const float* __restrict__ part,
                   float* __restrict__ weights_out,
                   float* __restrict__ ctx_out) {
    __shared__ float red[256];
    __shared__ float linv_s;
    const int b = blockIdx.x;
    const int t = threadIdx.x;

    const float4* wt4 = (const float4*)(wtilde + (size_t)b * SS);
    float4 vals[4];
    float l = 0.f;
#pragma unroll
    for (int i = 0; i < 4; ++i) {
        vals[i] = wt4[i * 256 + t];
        l += vals[i].x + vals[i].y + vals[i].z + vals[i].w;
    }
    red[t] = l;
    __syncthreads();
    for (int off = 128; off > 0; off >>= 1) {
        if (t < off) red[t] += red[t + off];
        __syncthreads();
    }
    if (t == 0) linv_s = 1.f / red[0];
    __syncthreads();
    const float linv = linv_s;

    float4* wo4 = (float4*)(weights_out + (size_t)b * SS);
#pragma unroll
    for (int i = 0; i < 4; ++i) {
        const float4 v = vals[i];
        wo4[i * 256 + t] =
            make_float4(v.x * linv, v.y * linv, v.z * linv, v.w * linv);
    }

    float a = 0.f;
#pragma unroll 8
    for (int c = 0; c < 64; ++c)
        a += part[((size_t)(b * 64 + c)) * HH + t];
    ctx_out[b * HH + t] = a * linv;
}

// ---------------------------------------------------------------------------
extern "C" void kernel_launch(void* const* d_in, const int* in_sizes, int n_in,
                              void* d_out, int out_size, void* d_ws, size_t ws_size,
                              hipStream_t stream) {
    const float* hidden = (const float*)d_in[0];
    const float* enc    = (const float*)d_in[1];
    const float* W1_w   = (const float*)d_in[2];
    const float* W1_b   = (const float*)d_in[3];
    const float* W2_w   = (const float*)d_in[4];
    const float* W2_b   = (const float*)d_in[5];
    const float* V_w    = (const float*)d_in[6];
    const float* V_b    = (const float*)d_in[7];
    (void)V_b;  // cancels in the shifted softmax

    float* out_weights = (float*)d_out;                 // B*S
    float* out_ctx     = (float*)d_out + BB * SS;       // B*H

    float* ws      = (float*)d_ws;
    float* ws_qq   = ws;                                 // 8192
    float* ws_wt   = ws_qq + BB * HH;                    // 131072
    float* ws_part = ws_wt + BB * SS;                    // 524288
    float* ws_M    = ws_part + BB * 64 * HH;             // 1
    ushort* ws_w2  = (ushort*)(ws_M + 4);                // 65536 bf16

    prep_kernel<<<dim3(256 + BB + 1), dim3(256), 0, stream>>>(
        W2_w, ws_w2, hidden, W1_w, W1_b, W2_b, V_w, ws_qq, ws_M);
    score_ctx_kernel<<<dim3(SS / 64, BB), dim3(256), 0, stream>>>(
        enc, ws_w2, ws_qq, V_w, ws_M, ws_wt, ws_part);
    finish_kernel<<<dim3(BB), dim3(256), 0, stream>>>(
        ws_wt, ws_part, out_weights, out_ctx);
}